// Round 8
// baseline (1155.286 us; speedup 1.0000x reference)
//
#include <hip/hip_runtime.h>

#define S_LEN 8192
#define C_CTX 21
#define E_DIM 128
#define G_DIM 36
#define H_DIM 1024
#define T_TAG 32
#define D_RAW 3444          // 21*(128+36)
#define DP 3456             // padded to multiple of 32
#define START_TAG 30
#define STOP_TAG 31
#define K_CHUNKS 128
#define L_CHUNK 64          // K_CHUNKS * L_CHUNK == S_LEN
#define NBLK 512            // one block-pair per CU; co-residency via __launch_bounds__(256,2)

typedef __bf16 bf16_t;
typedef __bf16 bf16x4 __attribute__((ext_vector_type(4)));
typedef __bf16 bf16x8 __attribute__((ext_vector_type(8)));
typedef float  f32x4  __attribute__((ext_vector_type(4)));

__device__ inline void async_copy16(const bf16_t* g, bf16_t* l) {
    __builtin_amdgcn_global_load_lds(
        (const __attribute__((address_space(1))) void*)g,
        (__attribute__((address_space(3))) void*)l, 16, 0, 0);
}

union alignas(16) SharedU {
    struct { bf16_t As[128 * 32]; bf16_t Bs[128 * 32]; } ge;            // 16 KB (gemm)
    struct { bf16_t As[128 * 64]; bf16_t Bs[32 * 64]; } fe;             // 20 KB (feats)
    struct { float fl[L_CHUNK * 32]; float vb[4][2][32]; } ca;          //  9 KB (crfA)
    struct { float AT[2][32][36]; float M[32][36]; float sgf[32]; } fo; // 14 KB (fold)
    struct { float gred[4]; } go;
};

__global__ __launch_bounds__(256, 2) void fused_k(
        const int* __restrict__ ctx, const float* __restrict__ gz,
        const float* __restrict__ emb, const float* __restrict__ w1,
        const float* __restrict__ b1, const float* __restrict__ w2,
        const float* __restrict__ b2, const float* __restrict__ trans,
        const int* __restrict__ lab,
        bf16_t* __restrict__ Xb, bf16_t* __restrict__ W1b, bf16_t* __restrict__ Hb,
        float* __restrict__ Fp, float* __restrict__ QT, float* __restrict__ sg,
        float* __restrict__ Q1, float* __restrict__ S1, float* __restrict__ gold_ws,
        unsigned* __restrict__ slots, unsigned* __restrict__ flag,
        float* __restrict__ out) {
    __shared__ SharedU sh;
    const int tid  = threadIdx.x;
    const int bx   = blockIdx.x;
    const int wave = tid >> 6, lane = tid & 63;

    // ---- grid barrier: slot-write + leader-scan + single flag broadcast ----
    // Poison-safe: tags never equal 0xAAAAAAAA; no pre-init needed.
    auto gbar = [&](unsigned e) {
        const unsigned tag = 0x5EED0000u + e;
        __syncthreads();
        if (tid == 0)
            __hip_atomic_store(&slots[bx], tag, __ATOMIC_RELEASE, __HIP_MEMORY_SCOPE_AGENT);
        if (bx == 0) {
            for (int i = tid; i < NBLK; i += 256) {
                int guard = 0;
                while (__hip_atomic_load(&slots[i], __ATOMIC_ACQUIRE, __HIP_MEMORY_SCOPE_AGENT) != tag
                       && guard < 2000000) { __builtin_amdgcn_s_sleep(8); ++guard; }
            }
            __syncthreads();
            if (tid == 0)
                __hip_atomic_store(flag, tag, __ATOMIC_RELEASE, __HIP_MEMORY_SCOPE_AGENT);
        }
        if (tid == 0) {
            int guard = 0;
            while (__hip_atomic_load(flag, __ATOMIC_ACQUIRE, __HIP_MEMORY_SCOPE_AGENT) != tag
                   && guard < 400000) { __builtin_amdgcn_s_sleep(64); ++guard; }
        }
        __syncthreads();
    };

    // ================= P0: build Xb (8192 rows) + W1b (1024 rows) ==========
    for (int u = bx; u < S_LEN + H_DIM; u += NBLK) {
        if (u < S_LEN) {
            const int s = u;
            for (int g = tid; g < DP / 4; g += 256) {
                float4 v = {0.f, 0.f, 0.f, 0.f};
                if (g < D_RAW / 4) {
                    const int c  = g / 41;
                    const int rg = g - c * 41;
                    if (rg < 32) v = *(const float4*)&emb[(size_t)ctx[s * C_CTX + c] * E_DIM + rg * 4];
                    else         v = *(const float4*)&gz[((size_t)s * C_CTX + c) * G_DIM + (rg - 32) * 4];
                }
                bf16x4 o = {(bf16_t)v.x, (bf16_t)v.y, (bf16_t)v.z, (bf16_t)v.w};
                *(bf16x4*)&Xb[(size_t)s * DP + g * 4] = o;
            }
        } else {
            const int h = u - S_LEN;
            for (int g = tid; g < DP / 4; g += 256) {
                float4 v = {0.f, 0.f, 0.f, 0.f};
                if (g < D_RAW / 4) v = *(const float4*)&w1[(size_t)h * D_RAW + g * 4];
                bf16x4 o = {(bf16_t)v.x, (bf16_t)v.y, (bf16_t)v.z, (bf16_t)v.w};
                *(bf16x4*)&W1b[(size_t)h * DP + g * 4] = o;
            }
        }
    }
    gbar(1);

    // ================= P1: gemm H = relu(X @ W1^T + b1) =====================
    {
        const int s0 = (bx & 63) * 128, h0 = (bx >> 6) * 128;
        const int wm = (wave & 1) * 64, wn = (wave >> 1) * 64;
        const int rowA = tid >> 2;
        const int kgs  = (tid & 3) ^ ((rowA >> 1) & 3);
        const int colA = kgs * 8;
        const bf16_t* gA0 = Xb + (size_t)(s0 + rowA) * DP + colA;
        const bf16_t* gA1 = Xb + (size_t)(s0 + rowA + 64) * DP + colA;
        const bf16_t* gB0 = W1b + (size_t)(h0 + rowA) * DP + colA;
        const bf16_t* gB1 = W1b + (size_t)(h0 + rowA + 64) * DP + colA;
        bf16_t* lA0 = &sh.ge.As[tid * 8];
        bf16_t* lA1 = &sh.ge.As[(tid + 256) * 8];
        bf16_t* lB0 = &sh.ge.Bs[tid * 8];
        bf16_t* lB1 = &sh.ge.Bs[(tid + 256) * 8];
        const int lrow = lane & 15;
        const int kq   = ((lane >> 4) ^ ((lrow >> 1) & 3)) * 8;

        f32x4 acc[4][4] = {};
        for (int k0 = 0; k0 < DP; k0 += 32) {
            async_copy16(gA0 + k0, lA0);
            async_copy16(gA1 + k0, lA1);
            async_copy16(gB0 + k0, lB0);
            async_copy16(gB1 + k0, lB1);
            __syncthreads();
            bf16x8 a[4], b[4];
#pragma unroll
            for (int mt = 0; mt < 4; ++mt)
                a[mt] = *(const bf16x8*)&sh.ge.As[(wm + mt * 16 + lrow) * 32 + kq];
#pragma unroll
            for (int nt = 0; nt < 4; ++nt)
                b[nt] = *(const bf16x8*)&sh.ge.Bs[(wn + nt * 16 + lrow) * 32 + kq];
#pragma unroll
            for (int mt = 0; mt < 4; ++mt)
#pragma unroll
                for (int nt = 0; nt < 4; ++nt)
                    acc[mt][nt] = __builtin_amdgcn_mfma_f32_16x16x32_bf16(a[mt], b[nt], acc[mt][nt], 0, 0, 0);
            __syncthreads();
        }
        const int crow = (lane >> 4) * 4;
        const int ccol = lane & 15;
#pragma unroll
        for (int nt = 0; nt < 4; ++nt) {
            const int j = h0 + wn + nt * 16 + ccol;
            const float bv = b1[j];
#pragma unroll
            for (int mt = 0; mt < 4; ++mt) {
#pragma unroll
                for (int r = 0; r < 4; ++r) {
                    const int s = s0 + wm + mt * 16 + crow + r;
                    const float v = acc[mt][nt][r] + bv;
                    Hb[(size_t)s * H_DIM + j] = (bf16_t)fmaxf(v, 0.f);
                }
            }
        }
    }
    gbar(2);

    // ====== P2: feats partials — block (x,y): Fp[s][y][:] = Htile @ w2_y^T ==
    {
        const int s0 = (bx & 63) * 128;
        const int y  = bx >> 6;
        const int h0 = y * 128;
        const int wm = wave * 32;
        const int arow = tid >> 3;
        const int akgs = (tid & 7) ^ (arow & 7);
        const bf16_t* gA = Hb + (size_t)(s0 + arow) * H_DIM + h0 + akgs * 8;
        const int brow = tid >> 3;
        const int bkgs = (tid & 7) ^ (brow & 7);
        const float* wp = w2 + (size_t)brow * H_DIM + h0 + bkgs * 8;
        bf16_t* lB = &sh.fe.Bs[tid * 8];
        const int lrow = lane & 15;

        f32x4 acc[2][2] = {};
#pragma unroll
        for (int k0 = 0; k0 < 128; k0 += 64) {
#pragma unroll
            for (int i = 0; i < 4; ++i)
                async_copy16(gA + (size_t)i * 32 * H_DIM + k0, &sh.fe.As[(tid + i * 256) * 8]);
            const float4 x0 = *(const float4*)(wp + k0);
            const float4 x1 = *(const float4*)(wp + k0 + 4);
            bf16x8 bb = {(bf16_t)x0.x, (bf16_t)x0.y, (bf16_t)x0.z, (bf16_t)x0.w,
                         (bf16_t)x1.x, (bf16_t)x1.y, (bf16_t)x1.z, (bf16_t)x1.w};
            *(bf16x8*)lB = bb;
            __syncthreads();
#pragma unroll
            for (int ks = 0; ks < 2; ++ks) {
                const int kq = ((ks * 4 + (lane >> 4)) ^ (lrow & 7)) * 8;
                bf16x8 a[2], b[2];
#pragma unroll
                for (int mt = 0; mt < 2; ++mt)
                    a[mt] = *(const bf16x8*)&sh.fe.As[(wm + mt * 16 + lrow) * 64 + kq];
#pragma unroll
                for (int nt = 0; nt < 2; ++nt)
                    b[nt] = *(const bf16x8*)&sh.fe.Bs[(nt * 16 + lrow) * 64 + kq];
#pragma unroll
                for (int mt = 0; mt < 2; ++mt)
#pragma unroll
                    for (int nt = 0; nt < 2; ++nt)
                        acc[mt][nt] = __builtin_amdgcn_mfma_f32_16x16x32_bf16(a[mt], b[nt], acc[mt][nt], 0, 0, 0);
            }
            __syncthreads();
        }
        const int crow = (lane >> 4) * 4;
        const int ccol = lane & 15;
#pragma unroll
        for (int nt = 0; nt < 2; ++nt) {
            const int j = nt * 16 + ccol;
#pragma unroll
            for (int mt = 0; mt < 2; ++mt) {
#pragma unroll
                for (int r = 0; r < 4; ++r) {
                    const int s = s0 + wm + mt * 16 + crow + r;
                    Fp[(size_t)(s * 8 + y) * T_TAG + j] = acc[mt][nt][r];
                }
            }
        }
    }
    gbar(3);

    // ================= P3: crfA — 512 units, L=64 chain =====================
    {
        const int n  = lane & 31;
        const int pl = lane >> 5;
        const int c  = bx >> 2;
        const int p  = ((bx & 3) << 3) + (wave << 1) + pl;
        const int s0 = c * L_CHUNK;
        for (int i = tid; i < L_CHUNK * 32; i += 256) {
            const int si = i >> 5, n2 = i & 31;
            float a = b2[n2];
            const float* fp = Fp + (size_t)((s0 + si) * 8) * T_TAG + n2;
#pragma unroll
            for (int y = 0; y < 8; ++y) a += fp[y * T_TAG];
            sh.ca.fl[i] = a;
        }
        __syncthreads();

        float et[32];
#pragma unroll
        for (int k = 0; k < 32; ++k) et[k] = __expf(trans[n * 32 + k]);

        float* vrow = &sh.ca.vb[wave][pl][0];
        float v  = __expf(trans[n * 32 + p] + sh.ca.fl[n]);
        float sgl = 0.f;
        for (int s = 1; s < L_CHUNK; ++s) {
            vrow[n] = v;
            __builtin_amdgcn_s_waitcnt(0xC07F);   // lgkmcnt(0), wave-coherent LDS
            float a0 = 0.f, a1 = 0.f, a2 = 0.f, a3 = 0.f;
#pragma unroll
            for (int q = 0; q < 8; ++q) {
                const float4 wv = *(const float4*)&vrow[q * 4];
                a0 = __builtin_fmaf(et[q * 4 + 0], wv.x, a0);
                a1 = __builtin_fmaf(et[q * 4 + 1], wv.y, a1);
                a2 = __builtin_fmaf(et[q * 4 + 2], wv.z, a2);
                a3 = __builtin_fmaf(et[q * 4 + 3], wv.w, a3);
            }
            v = __expf(sh.ca.fl[s * 32 + n]) * ((a0 + a1) + (a2 + a3));
            if ((s & 7) == 7) {
                float m = v;
#pragma unroll
                for (int off = 16; off; off >>= 1) m = fmaxf(m, __shfl_xor(m, off, 32));
                if (m > 0.f) { v *= 1.0f / m; sgl += __logf(m); }
            }
        }
        QT[(size_t)(c * 32 + p) * 32 + n] = v;
        if (n == 0) sg[c * 32 + p] = sgl;
    }
    gbar(4);

    // ---- 256-thread fold body (verified in R7) ----
    const int fn = tid & 31, fpq = tid >> 5;
    auto fold_body = [&](const float* Qin, const float* Sin, int c0, int fold,
                         float* Qout, float* Sout, int bxout, int final_) {
        float sA[4];
#pragma unroll
        for (int j = 0; j < 4; ++j) {
            const int p = fpq * 4 + j;
            sh.fo.AT[0][p][fn] = Qin[(size_t)(c0 * 32 + p) * 32 + fn];
            sA[j] = Sin[c0 * 32 + p];
        }
        __syncthreads();
        int cur = 0;
        for (int i = 1; i < fold; ++i) {
            const float sMn = Sin[(c0 + i) * 32 + fn];
            float mmax = sMn;
#pragma unroll
            for (int off = 16; off; off >>= 1) mmax = fmaxf(mmax, __shfl_xor(mmax, off, 32));
#pragma unroll
            for (int j = 0; j < 4; ++j) {
                const int k = fpq * 4 + j;
                const float sMk = __shfl(sMn, k, 32);
                sh.fo.M[fn][k] = Qin[(size_t)((c0 + i) * 32 + k) * 32 + fn] * __expf(sMk - mmax);
            }
            __syncthreads();
            float4 mrow[8];
#pragma unroll
            for (int q = 0; q < 8; ++q) mrow[q] = *(const float4*)&sh.fo.M[fn][q * 4];
            float acc[4];
#pragma unroll
            for (int j = 0; j < 4; ++j) {
                const int p = fpq * 4 + j;
                float a0 = 0.f, a1 = 0.f, a2 = 0.f, a3 = 0.f;
#pragma unroll
                for (int q = 0; q < 8; ++q) {
                    const float4 av = *(const float4*)&sh.fo.AT[cur][p][q * 4];
                    a0 = __builtin_fmaf(mrow[q].x, av.x, a0);
                    a1 = __builtin_fmaf(mrow[q].y, av.y, a1);
                    a2 = __builtin_fmaf(mrow[q].z, av.z, a2);
                    a3 = __builtin_fmaf(mrow[q].w, av.w, a3);
                }
                acc[j] = (a0 + a1) + (a2 + a3);
            }
#pragma unroll
            for (int j = 0; j < 4; ++j) {
                float cm = acc[j];
#pragma unroll
                for (int off = 16; off; off >>= 1) cm = fmaxf(cm, __shfl_xor(cm, off, 32));
                cm = fmaxf(cm, 1e-37f);
                sh.fo.AT[cur ^ 1][fpq * 4 + j][fn] = acc[j] / cm;
                sA[j] += mmax + __logf(cm);
            }
            __syncthreads();
            cur ^= 1;
        }
        if (!final_) {
#pragma unroll
            for (int j = 0; j < 4; ++j) {
                const int p = fpq * 4 + j;
                Qout[(size_t)(bxout * 32 + p) * 32 + fn] = sh.fo.AT[cur][p][fn];
                if (fn == 0) Sout[bxout * 32 + p] = sA[j];
            }
        } else {
            if (fn == 0) {
#pragma unroll
                for (int j = 0; j < 4; ++j) sh.fo.sgf[fpq * 4 + j] = sA[j];
            }
            __syncthreads();
            if (tid < 32) {
                float v = sh.fo.AT[cur][START_TAG][tid] * __expf(trans[STOP_TAG * T_TAG + tid]);
#pragma unroll
                for (int off = 16; off; off >>= 1) v += __shfl_xor(v, off, 32);
                if (tid == 0) out[0] = sh.fo.sgf[START_TAG] + __logf(v) - gold_ws[0];
            }
        }
    };

    // ====== P4: fold level 1 (blocks 0..15, fold-8) + gold (block 16) =======
    if (bx < 16) {
        fold_body(QT, sg, bx * 8, 8, Q1, S1, bx, 0);
    } else if (bx == 16) {
        float ga = 0.f;
        for (int s = tid; s < S_LEN; s += 256) {
            const int tg = lab[s];
            const float* fp = Fp + (size_t)(s * 8) * T_TAG + tg;
#pragma unroll
            for (int y = 0; y < 8; ++y) ga += fp[y * T_TAG];
            ga += b2[tg];
            const int tp = (s == 0) ? START_TAG : lab[s - 1];
            ga += trans[tg * T_TAG + tp];
        }
        if (tid == 0) ga += trans[STOP_TAG * T_TAG + lab[S_LEN - 1]];
#pragma unroll
        for (int off = 32; off; off >>= 1) ga += __shfl_down(ga, off, 64);
        if (lane == 0) sh.go.gred[wave] = ga;
        __syncthreads();
        if (tid == 0) gold_ws[0] = sh.go.gred[0] + sh.go.gred[1] + sh.go.gred[2] + sh.go.gred[3];
    }
    gbar(5);

    // ================= P5: final fold-16 + NLL (block 0) ====================
    if (bx == 0) fold_body(Q1, S1, 0, 16, nullptr, nullptr, 0, 1);
}

// ---------------- launch ----------------
extern "C" void kernel_launch(void* const* d_in, const int* in_sizes, int n_in,
                              void* d_out, int out_size, void* d_ws, size_t ws_size,
                              hipStream_t stream) {
    const int*   ctx   = (const int*)d_in[0];
    const float* gz    = (const float*)d_in[1];
    const int*   lab   = (const int*)d_in[2];
    const float* emb   = (const float*)d_in[3];
    const float* w1    = (const float*)d_in[4];
    const float* b1    = (const float*)d_in[5];
    const float* w2    = (const float*)d_in[6];
    const float* b2    = (const float*)d_in[7];
    const float* trans = (const float*)d_in[8];
    float* out = (float*)d_out;

    char* ws = (char*)d_ws;
    bf16_t* Xb  = (bf16_t*)(ws + 0);               // 8192*3456*2 = 56,623,104 (dead after P1)
    bf16_t* W1b = (bf16_t*)(ws + 56623104);        // 1024*3456*2 =  7,077,888
    bf16_t* Hb  = (bf16_t*)(ws + 63700992);        // 8192*1024*2 = 16,777,216
    // overlays inside the Xb region (written only after gemm phase):
    float*  Q1   = (float*)(ws + 0);               // 16*32*32*4
    float*  S1   = (float*)(ws + 65536);           // 16*32*4
    float*  gold = (float*)(ws + 131072);          // 4 B
    float*  QT   = (float*)(ws + 1048576);         // 128*32*32*4 = 524,288
    float*  sg   = (float*)(ws + 2097152);         // 128*32*4    =  16,384
    float*  Fp   = (float*)(ws + 4194304);         // 8192*8*32*4 = 8,388,608
    unsigned* slots = (unsigned*)(ws + 81526784);  // 512*4
    unsigned* flag  = (unsigned*)(ws + 81528832);  // 4

    fused_k<<<NBLK, 256, 0, stream>>>(ctx, gz, emb, w1, b1, w2, b2, trans, lab,
                                      Xb, W1b, Hb, Fp, QT, sg, Q1, S1, gold,
                                      slots, flag, out);
}

// Round 9
// 427.154 us; speedup vs baseline: 2.7046x; 2.7046x over previous
//
#include <hip/hip_runtime.h>

#define S_LEN 8192
#define C_CTX 21
#define E_DIM 128
#define G_DIM 36
#define H_DIM 1024
#define T_TAG 32
#define D_RAW 3444          // 21*(128+36)
#define DP 3456             // padded to multiple of 32
#define START_TAG 30
#define STOP_TAG 31
#define K_CHUNKS 64
#define L_CHUNK 128         // K_CHUNKS * L_CHUNK == S_LEN

typedef __bf16 bf16_t;
typedef __bf16 bf16x4 __attribute__((ext_vector_type(4)));
typedef __bf16 bf16x8 __attribute__((ext_vector_type(8)));
typedef float  f32x4  __attribute__((ext_vector_type(4)));

__device__ inline void async_copy16(const bf16_t* g, bf16_t* l) {
    __builtin_amdgcn_global_load_lds(
        (const __attribute__((address_space(1))) void*)g,
        (__attribute__((address_space(3))) void*)l, 16, 0, 0);
}

// ---------------- Phase 0: materialize padded bf16 X and W1 ----------------
__global__ void build_all(const int* __restrict__ ctx, const float* __restrict__ gz,
                          const float* __restrict__ emb, const float* __restrict__ w1,
                          bf16_t* __restrict__ X, bf16_t* __restrict__ W) {
    const int b = blockIdx.x;
    if (b < S_LEN) {
        const int s = b;
        for (int g = threadIdx.x; g < DP / 4; g += 256) {
            float4 v = {0.f, 0.f, 0.f, 0.f};
            if (g < D_RAW / 4) {
                const int c  = g / 41;
                const int rg = g - c * 41;
                if (rg < 32) v = *(const float4*)&emb[(size_t)ctx[s * C_CTX + c] * E_DIM + rg * 4];
                else         v = *(const float4*)&gz[((size_t)s * C_CTX + c) * G_DIM + (rg - 32) * 4];
            }
            bf16x4 o = {(bf16_t)v.x, (bf16_t)v.y, (bf16_t)v.z, (bf16_t)v.w};
            *(bf16x4*)&X[(size_t)s * DP + g * 4] = o;
        }
    } else {
        const int h = b - S_LEN;
        for (int g = threadIdx.x; g < DP / 4; g += 256) {
            float4 v = {0.f, 0.f, 0.f, 0.f};
            if (g < D_RAW / 4) v = *(const float4*)&w1[(size_t)h * D_RAW + g * 4];
            bf16x4 o = {(bf16_t)v.x, (bf16_t)v.y, (bf16_t)v.z, (bf16_t)v.w};
            *(bf16x4*)&W[(size_t)h * DP + g * 4] = o;
        }
    }
}

// ---------------- Phase 1+2: H-tile GEMM + fused feats partial -------------
// Block (x=bx&63, y=bx>>6): computes H[s-tile][h-tile] = relu(X@W1^T+b1) in
// regs, stages it to LDS (bf16, kg^(row&7) swizzle), then
// Fp[s][y][t] = Htile @ w2[:, h-tile]^T  (fp32 partial, summed in crfA).
union alignas(16) SharedGF {
    struct { bf16_t As[128 * 32]; bf16_t Bs[128 * 32]; } ge;   // 16 KB (K-loop)
    struct { bf16_t ht[128 * 128]; bf16_t w2s[32 * 128]; } fe; // 40 KB (epilogue)
};

__global__ __launch_bounds__(256) void gemm_feats(const bf16_t* __restrict__ X,
                                                  const bf16_t* __restrict__ W,
                                                  const float* __restrict__ b1,
                                                  const float* __restrict__ w2,
                                                  float* __restrict__ Fp) {
    __shared__ SharedGF sh;
    const int tid  = threadIdx.x;
    const int wave = tid >> 6, lane = tid & 63;
    const int s0 = (blockIdx.x & 63) * 128;
    const int y  = blockIdx.x >> 6;
    const int h0 = y * 128;
    const int wm = (wave & 1) * 64, wn = (wave >> 1) * 64;

    const int rowA = tid >> 2;
    const int kgs  = (tid & 3) ^ ((rowA >> 1) & 3);
    const int colA = kgs * 8;
    const bf16_t* gA0 = X + (size_t)(s0 + rowA) * DP + colA;
    const bf16_t* gA1 = X + (size_t)(s0 + rowA + 64) * DP + colA;
    const bf16_t* gB0 = W + (size_t)(h0 + rowA) * DP + colA;
    const bf16_t* gB1 = W + (size_t)(h0 + rowA + 64) * DP + colA;
    bf16_t* lA0 = &sh.ge.As[tid * 8];
    bf16_t* lA1 = &sh.ge.As[(tid + 256) * 8];
    bf16_t* lB0 = &sh.ge.Bs[tid * 8];
    bf16_t* lB1 = &sh.ge.Bs[(tid + 256) * 8];

    const int lrow = lane & 15;
    const int kq   = ((lane >> 4) ^ ((lrow >> 1) & 3)) * 8;

    f32x4 acc[4][4] = {};
    for (int k0 = 0; k0 < DP; k0 += 32) {
        async_copy16(gA0 + k0, lA0);
        async_copy16(gA1 + k0, lA1);
        async_copy16(gB0 + k0, lB0);
        async_copy16(gB1 + k0, lB1);
        __syncthreads();
        bf16x8 a[4], b[4];
#pragma unroll
        for (int mt = 0; mt < 4; ++mt)
            a[mt] = *(const bf16x8*)&sh.ge.As[(wm + mt * 16 + lrow) * 32 + kq];
#pragma unroll
        for (int nt = 0; nt < 4; ++nt)
            b[nt] = *(const bf16x8*)&sh.ge.Bs[(wn + nt * 16 + lrow) * 32 + kq];
#pragma unroll
        for (int mt = 0; mt < 4; ++mt)
#pragma unroll
            for (int nt = 0; nt < 4; ++nt)
                acc[mt][nt] = __builtin_amdgcn_mfma_f32_16x16x32_bf16(a[mt], b[nt], acc[mt][nt], 0, 0, 0);
        __syncthreads();
    }

    // ---- epilogue A: H-tile -> LDS (bias+relu+bf16), swizzled kg^(row&7) ----
    const int crow = (lane >> 4) * 4;
    const int ccol = lane & 15;
#pragma unroll
    for (int nt = 0; nt < 4; ++nt) {
        const int j  = wn + nt * 16 + ccol;          // local col 0..127
        const float bv = b1[h0 + j];
#pragma unroll
        for (int mt = 0; mt < 4; ++mt) {
#pragma unroll
            for (int r = 0; r < 4; ++r) {
                const int row = wm + mt * 16 + crow + r;
                const float v = fmaxf(acc[mt][nt][r] + bv, 0.f);
                sh.fe.ht[row * 128 + (((j >> 3) ^ (row & 7)) << 3) + (j & 7)] = (bf16_t)v;
            }
        }
    }
    // ---- stage w2 slice (32 x 128) -> LDS, same swizzle ----
#pragma unroll
    for (int i = 0; i < 2; ++i) {
        const int q   = tid + i * 256;               // 512 chunks of 8
        const int t   = q >> 4;                      // 0..31
        const int kgL = q & 15;
        const int kgS = kgL ^ (t & 7);
        const float4 x0 = *(const float4*)&w2[(size_t)t * H_DIM + h0 + kgS * 8];
        const float4 x1 = *(const float4*)&w2[(size_t)t * H_DIM + h0 + kgS * 8 + 4];
        bf16x8 bb = {(bf16_t)x0.x, (bf16_t)x0.y, (bf16_t)x0.z, (bf16_t)x0.w,
                     (bf16_t)x1.x, (bf16_t)x1.y, (bf16_t)x1.z, (bf16_t)x1.w};
        *(bf16x8*)&sh.fe.w2s[t * 128 + kgL * 8] = bb;
    }
    __syncthreads();

    // ---- epilogue B: Fp[s][y][:] = Htile @ w2s^T, M=128 N=32 K=128 ----
    const int wm2 = wave * 32;
    f32x4 acc2[2][2] = {};
#pragma unroll
    for (int ks = 0; ks < 4; ++ks) {
        bf16x8 a[2], b[2];
#pragma unroll
        for (int mt = 0; mt < 2; ++mt) {
            const int row = wm2 + mt * 16 + lrow;
            const int kg  = (ks * 4 + (lane >> 4)) ^ (row & 7);
            a[mt] = *(const bf16x8*)&sh.fe.ht[row * 128 + kg * 8];
        }
#pragma unroll
        for (int nt = 0; nt < 2; ++nt) {
            const int row = nt * 16 + lrow;
            const int kg  = (ks * 4 + (lane >> 4)) ^ (row & 7);
            b[nt] = *(const bf16x8*)&sh.fe.w2s[row * 128 + kg * 8];
        }
#pragma unroll
        for (int mt = 0; mt < 2; ++mt)
#pragma unroll
            for (int nt = 0; nt < 2; ++nt)
                acc2[mt][nt] = __builtin_amdgcn_mfma_f32_16x16x32_bf16(a[mt], b[nt], acc2[mt][nt], 0, 0, 0);
    }
#pragma unroll
    for (int nt = 0; nt < 2; ++nt) {
        const int t = nt * 16 + ccol;
#pragma unroll
        for (int mt = 0; mt < 2; ++mt) {
#pragma unroll
            for (int r = 0; r < 4; ++r) {
                const int s = s0 + wm2 + mt * 16 + crow + r;
                Fp[(size_t)(s * 8 + y) * T_TAG + t] = acc2[mt][nt][r];
            }
        }
    }
}

// ---------------- CRF pass A: 64 chunks of L=128, grid 256 -----------------
__global__ __launch_bounds__(256) void crfA(const float* __restrict__ Fp,
                                            const float* __restrict__ b2,
                                            const float* __restrict__ trans,
                                            float* __restrict__ QT,
                                            float* __restrict__ sigma) {
    __shared__ float fl[L_CHUNK * 32];
    __shared__ float vb[4][2][32];
    const int c    = blockIdx.x >> 2;
    const int tid  = threadIdx.x;
    const int wave = tid >> 6;
    const int lane = tid & 63;
    const int n    = lane & 31;
    const int pl   = lane >> 5;
    const int p    = ((blockIdx.x & 3) << 3) + (wave << 1) + pl;
    const int s0   = c * L_CHUNK;
    for (int i = tid; i < L_CHUNK * 32; i += 256) {
        const int si = i >> 5, n2 = i & 31;
        float a = b2[n2];
        const float* fp = Fp + (size_t)((s0 + si) * 8) * T_TAG + n2;
#pragma unroll
        for (int yy = 0; yy < 8; ++yy) a += fp[yy * T_TAG];
        fl[i] = a;
    }
    __syncthreads();

    float et[32];
#pragma unroll
    for (int k = 0; k < 32; ++k) et[k] = __expf(trans[n * 32 + k]);

    float* vrow = &vb[wave][pl][0];
    float v  = __expf(trans[n * 32 + p] + fl[n]);
    float sg = 0.f;
    for (int s = 1; s < L_CHUNK; ++s) {
        vrow[n] = v;
        __builtin_amdgcn_s_waitcnt(0xC07F);   // lgkmcnt(0): wave-coherent LDS
        float a0 = 0.f, a1 = 0.f, a2 = 0.f, a3 = 0.f;
#pragma unroll
        for (int q = 0; q < 8; ++q) {
            const float4 wv = *(const float4*)&vrow[q * 4];
            a0 = __builtin_fmaf(et[q * 4 + 0], wv.x, a0);
            a1 = __builtin_fmaf(et[q * 4 + 1], wv.y, a1);
            a2 = __builtin_fmaf(et[q * 4 + 2], wv.z, a2);
            a3 = __builtin_fmaf(et[q * 4 + 3], wv.w, a3);
        }
        v = __expf(fl[s * 32 + n]) * ((a0 + a1) + (a2 + a3));
        if ((s & 7) == 7) {
            float m = v;
#pragma unroll
            for (int off = 16; off; off >>= 1) m = fmaxf(m, __shfl_xor(m, off, 32));
            if (m > 0.f) { v *= 1.0f / m; sg += __logf(m); }
        }
    }
    QT[(size_t)(c * 32 + p) * 32 + n] = v;
    if (n == 0) sigma[c * 32 + p] = sg;
}

// ---------------- final: gold + fold-64 + NLL, one block -------------------
__global__ __launch_bounds__(1024) void final_k(const float* __restrict__ Qin,
                                                const float* __restrict__ Sin,
                                                const float* __restrict__ trans,
                                                const float* __restrict__ Fp,
                                                const float* __restrict__ b2,
                                                const int* __restrict__ lab,
                                                float* __restrict__ out) {
    __shared__ float A[2][32][33];
    __shared__ float M[32][33];
    __shared__ float sgf[32];
    __shared__ float gred[16];
    __shared__ float gold_s;

    const int t = threadIdx.x;
    const int p = t >> 5, n = t & 31;

    // gold score from Fp partials
    float ga = 0.f;
    for (int s = t; s < S_LEN; s += 1024) {
        const int tg = lab[s];
        const float* fp = Fp + (size_t)(s * 8) * T_TAG + tg;
#pragma unroll
        for (int yy = 0; yy < 8; ++yy) ga += fp[yy * T_TAG];
        ga += b2[tg];
        const int tp = (s == 0) ? START_TAG : lab[s - 1];
        ga += trans[tg * T_TAG + tp];
    }
    if (t == 0) ga += trans[STOP_TAG * T_TAG + lab[S_LEN - 1]];
#pragma unroll
    for (int off = 32; off; off >>= 1) ga += __shfl_down(ga, off, 64);
    if ((t & 63) == 0) gred[t >> 6] = ga;

    // fold 64 chunk matrices
    A[0][n][p] = Qin[(size_t)(0 * 32 + p) * 32 + n];
    float sA = Sin[p];
    float mreg = Qin[(size_t)(1 * 32 + p) * 32 + n];
    int cur = 0;

    for (int i = 1; i < K_CHUNKS; ++i) {
        const float sMn = Sin[i * 32 + n];
        float mmax = sMn;
#pragma unroll
        for (int off = 16; off; off >>= 1) mmax = fmaxf(mmax, __shfl_xor(mmax, off, 32));
        const float sMp = Sin[i * 32 + p];
        M[n][p] = mreg * __expf(sMp - mmax);
        if (i + 1 < K_CHUNKS) mreg = Qin[(size_t)((i + 1) * 32 + p) * 32 + n];
        __syncthreads();
        float acc = 0.f;
#pragma unroll 8
        for (int k = 0; k < 32; ++k)
            acc += M[n][k] * A[cur][k][p];
        float cm = acc;
#pragma unroll
        for (int off = 16; off; off >>= 1) cm = fmaxf(cm, __shfl_xor(cm, off, 32));
        cm = fmaxf(cm, 1e-37f);
        A[cur ^ 1][n][p] = acc / cm;
        sA = sA + mmax + __logf(cm);
        __syncthreads();
        cur ^= 1;
    }

    if (n == 0) sgf[p] = sA;
    if (t == 0) {
        float s = 0.f;
#pragma unroll
        for (int i = 0; i < 16; ++i) s += gred[i];
        gold_s = s;
    }
    __syncthreads();
    if (t < 32) {
        float v = A[cur][t][START_TAG] * __expf(trans[STOP_TAG * T_TAG + t]);
#pragma unroll
        for (int off = 16; off; off >>= 1) v += __shfl_xor(v, off, 32);
        if (t == 0) out[0] = sgf[START_TAG] + __logf(v) - gold_s;
    }
}

// ---------------- launch ----------------
extern "C" void kernel_launch(void* const* d_in, const int* in_sizes, int n_in,
                              void* d_out, int out_size, void* d_ws, size_t ws_size,
                              hipStream_t stream) {
    const int*   ctx   = (const int*)d_in[0];
    const float* gz    = (const float*)d_in[1];
    const int*   lab   = (const int*)d_in[2];
    const float* emb   = (const float*)d_in[3];
    const float* w1    = (const float*)d_in[4];
    const float* b1    = (const float*)d_in[5];
    const float* w2    = (const float*)d_in[6];
    const float* b2    = (const float*)d_in[7];
    const float* trans = (const float*)d_in[8];
    float* out = (float*)d_out;

    char* ws = (char*)d_ws;
    bf16_t* Xb  = (bf16_t*)(ws + 0);               // 8192*3456*2 = 56,623,104
    bf16_t* W1b = (bf16_t*)(ws + 56623104);        // 1024*3456*2 =  7,077,888
    float*  Fp  = (float*)(ws + 63700992);         // 8192*8*32*4 =  8,388,608
    float*  QT  = (float*)(ws + 72089600);         // 64*32*32*4  =    262,144
    float*  sg  = (float*)(ws + 72351744);         // 64*32*4     =      8,192

    build_all<<<S_LEN + H_DIM, 256, 0, stream>>>(ctx, gz, emb, w1, Xb, W1b);
    gemm_feats<<<512, 256, 0, stream>>>(Xb, W1b, b1, w2, Fp);
    crfA<<<K_CHUNKS * 4, 256, 0, stream>>>(Fp, b2, trans, QT, sg);
    final_k<<<1, 1024, 0, stream>>>(QT, sg, trans, Fp, b2, lab, out);
}

// Round 10
// 319.641 us; speedup vs baseline: 3.6143x; 1.3364x over previous
//
#include <hip/hip_runtime.h>

#define S_LEN 8192
#define C_CTX 21
#define E_DIM 128
#define G_DIM 36
#define H_DIM 1024
#define T_TAG 32
#define D_RAW 3444          // 21*(128+36)
#define DP 3456             // padded to multiple of 32
#define START_TAG 30
#define STOP_TAG 31
#define K_CHUNKS 64
#define L_CHUNK 128         // K_CHUNKS * L_CHUNK == S_LEN

typedef __bf16 bf16_t;
typedef __bf16 bf16x4 __attribute__((ext_vector_type(4)));
typedef __bf16 bf16x8 __attribute__((ext_vector_type(8)));
typedef float  f32x4  __attribute__((ext_vector_type(4)));

__device__ inline void async_copy16(const bf16_t* g, bf16_t* l) {
    __builtin_amdgcn_global_load_lds(
        (const __attribute__((address_space(1))) void*)g,
        (__attribute__((address_space(3))) void*)l, 16, 0, 0);
}

// ---------------- Phase 0: materialize padded bf16 X and W1 ----------------
__global__ void build_all(const int* __restrict__ ctx, const float* __restrict__ gz,
                          const float* __restrict__ emb, const float* __restrict__ w1,
                          bf16_t* __restrict__ X, bf16_t* __restrict__ W) {
    const int b = blockIdx.x;
    if (b < S_LEN) {
        const int s = b;
        for (int g = threadIdx.x; g < DP / 4; g += 256) {
            float4 v = {0.f, 0.f, 0.f, 0.f};
            if (g < D_RAW / 4) {
                const int c  = g / 41;
                const int rg = g - c * 41;
                if (rg < 32) v = *(const float4*)&emb[(size_t)ctx[s * C_CTX + c] * E_DIM + rg * 4];
                else         v = *(const float4*)&gz[((size_t)s * C_CTX + c) * G_DIM + (rg - 32) * 4];
            }
            bf16x4 o = {(bf16_t)v.x, (bf16_t)v.y, (bf16_t)v.z, (bf16_t)v.w};
            *(bf16x4*)&X[(size_t)s * DP + g * 4] = o;
        }
    } else {
        const int h = b - S_LEN;
        for (int g = threadIdx.x; g < DP / 4; g += 256) {
            float4 v = {0.f, 0.f, 0.f, 0.f};
            if (g < D_RAW / 4) v = *(const float4*)&w1[(size_t)h * D_RAW + g * 4];
            bf16x4 o = {(bf16_t)v.x, (bf16_t)v.y, (bf16_t)v.z, (bf16_t)v.w};
            *(bf16x4*)&W[(size_t)h * DP + g * 4] = o;
        }
    }
}

// ---------------- Phase 1+2: H-tile GEMM + fused feats partial -------------
union alignas(16) SharedGF {
    struct { bf16_t As[128 * 32]; bf16_t Bs[128 * 32]; } ge;   // 16 KB (K-loop)
    struct { bf16_t ht[128 * 128]; bf16_t w2s[32 * 128]; } fe; // 40 KB (epilogue)
};

__global__ __launch_bounds__(256) void gemm_feats(const bf16_t* __restrict__ X,
                                                  const bf16_t* __restrict__ W,
                                                  const float* __restrict__ b1,
                                                  const float* __restrict__ w2,
                                                  float* __restrict__ Fp) {
    __shared__ SharedGF sh;
    const int tid  = threadIdx.x;
    const int wave = tid >> 6, lane = tid & 63;
    const int s0 = (blockIdx.x & 63) * 128;
    const int y  = blockIdx.x >> 6;
    const int h0 = y * 128;
    const int wm = (wave & 1) * 64, wn = (wave >> 1) * 64;

    const int rowA = tid >> 2;
    const int kgs  = (tid & 3) ^ ((rowA >> 1) & 3);
    const int colA = kgs * 8;
    const bf16_t* gA0 = X + (size_t)(s0 + rowA) * DP + colA;
    const bf16_t* gA1 = X + (size_t)(s0 + rowA + 64) * DP + colA;
    const bf16_t* gB0 = W + (size_t)(h0 + rowA) * DP + colA;
    const bf16_t* gB1 = W + (size_t)(h0 + rowA + 64) * DP + colA;
    bf16_t* lA0 = &sh.ge.As[tid * 8];
    bf16_t* lA1 = &sh.ge.As[(tid + 256) * 8];
    bf16_t* lB0 = &sh.ge.Bs[tid * 8];
    bf16_t* lB1 = &sh.ge.Bs[(tid + 256) * 8];

    const int lrow = lane & 15;
    const int kq   = ((lane >> 4) ^ ((lrow >> 1) & 3)) * 8;

    f32x4 acc[4][4] = {};
    for (int k0 = 0; k0 < DP; k0 += 32) {
        async_copy16(gA0 + k0, lA0);
        async_copy16(gA1 + k0, lA1);
        async_copy16(gB0 + k0, lB0);
        async_copy16(gB1 + k0, lB1);
        __syncthreads();
        bf16x8 a[4], b[4];
#pragma unroll
        for (int mt = 0; mt < 4; ++mt)
            a[mt] = *(const bf16x8*)&sh.ge.As[(wm + mt * 16 + lrow) * 32 + kq];
#pragma unroll
        for (int nt = 0; nt < 4; ++nt)
            b[nt] = *(const bf16x8*)&sh.ge.Bs[(wn + nt * 16 + lrow) * 32 + kq];
#pragma unroll
        for (int mt = 0; mt < 4; ++mt)
#pragma unroll
            for (int nt = 0; nt < 4; ++nt)
                acc[mt][nt] = __builtin_amdgcn_mfma_f32_16x16x32_bf16(a[mt], b[nt], acc[mt][nt], 0, 0, 0);
        __syncthreads();
    }

    // ---- epilogue A: H-tile -> LDS (bias+relu+bf16), swizzled kg^(row&7) ----
    const int crow = (lane >> 4) * 4;
    const int ccol = lane & 15;
#pragma unroll
    for (int nt = 0; nt < 4; ++nt) {
        const int j  = wn + nt * 16 + ccol;
        const float bv = b1[h0 + j];
#pragma unroll
        for (int mt = 0; mt < 4; ++mt) {
#pragma unroll
            for (int r = 0; r < 4; ++r) {
                const int row = wm + mt * 16 + crow + r;
                const float v = fmaxf(acc[mt][nt][r] + bv, 0.f);
                sh.fe.ht[row * 128 + (((j >> 3) ^ (row & 7)) << 3) + (j & 7)] = (bf16_t)v;
            }
        }
    }
#pragma unroll
    for (int i = 0; i < 2; ++i) {
        const int q   = tid + i * 256;
        const int t   = q >> 4;
        const int kgL = q & 15;
        const int kgS = kgL ^ (t & 7);
        const float4 x0 = *(const float4*)&w2[(size_t)t * H_DIM + h0 + kgS * 8];
        const float4 x1 = *(const float4*)&w2[(size_t)t * H_DIM + h0 + kgS * 8 + 4];
        bf16x8 bb = {(bf16_t)x0.x, (bf16_t)x0.y, (bf16_t)x0.z, (bf16_t)x0.w,
                     (bf16_t)x1.x, (bf16_t)x1.y, (bf16_t)x1.z, (bf16_t)x1.w};
        *(bf16x8*)&sh.fe.w2s[t * 128 + kgL * 8] = bb;
    }
    __syncthreads();

    const int wm2 = wave * 32;
    f32x4 acc2[2][2] = {};
#pragma unroll
    for (int ks = 0; ks < 4; ++ks) {
        bf16x8 a[2], b[2];
#pragma unroll
        for (int mt = 0; mt < 2; ++mt) {
            const int row = wm2 + mt * 16 + lrow;
            const int kg  = (ks * 4 + (lane >> 4)) ^ (row & 7);
            a[mt] = *(const bf16x8*)&sh.fe.ht[row * 128 + kg * 8];
        }
#pragma unroll
        for (int nt = 0; nt < 2; ++nt) {
            const int row = nt * 16 + lrow;
            const int kg  = (ks * 4 + (lane >> 4)) ^ (row & 7);
            b[nt] = *(const bf16x8*)&sh.fe.w2s[row * 128 + kg * 8];
        }
#pragma unroll
        for (int mt = 0; mt < 2; ++mt)
#pragma unroll
            for (int nt = 0; nt < 2; ++nt)
                acc2[mt][nt] = __builtin_amdgcn_mfma_f32_16x16x32_bf16(a[mt], b[nt], acc2[mt][nt], 0, 0, 0);
    }
#pragma unroll
    for (int nt = 0; nt < 2; ++nt) {
        const int t = nt * 16 + ccol;
#pragma unroll
        for (int mt = 0; mt < 2; ++mt) {
#pragma unroll
            for (int r = 0; r < 4; ++r) {
                const int s = s0 + wm2 + mt * 16 + crow + r;
                Fp[(size_t)(s * 8 + y) * T_TAG + t] = acc2[mt][nt][r];
            }
        }
    }
}

// ---------------- CRF pass A: 64 chunks of L=128, grid 256 -----------------
// Emits Q in BOTH bf16 layouts: Qnb[c][n][p] (row-major, A-operand reads)
// and QTb[c][p][n] (transposed, B-operand reads). sigma stays fp32.
__global__ __launch_bounds__(256) void crfA(const float* __restrict__ Fp,
                                            const float* __restrict__ b2,
                                            const float* __restrict__ trans,
                                            bf16_t* __restrict__ Qnb,
                                            bf16_t* __restrict__ QTb,
                                            float* __restrict__ sigma) {
    __shared__ float fl[L_CHUNK * 32];
    __shared__ float vb[4][2][32];
    const int c    = blockIdx.x >> 2;
    const int tid  = threadIdx.x;
    const int wave = tid >> 6;
    const int lane = tid & 63;
    const int n    = lane & 31;
    const int pl   = lane >> 5;
    const int p    = ((blockIdx.x & 3) << 3) + (wave << 1) + pl;
    const int s0   = c * L_CHUNK;
    for (int i = tid; i < L_CHUNK * 32; i += 256) {
        const int si = i >> 5, n2 = i & 31;
        float a = b2[n2];
        const float* fp = Fp + (size_t)((s0 + si) * 8) * T_TAG + n2;
#pragma unroll
        for (int yy = 0; yy < 8; ++yy) a += fp[yy * T_TAG];
        fl[i] = a;
    }
    __syncthreads();

    float et[32];
#pragma unroll
    for (int k = 0; k < 32; ++k) et[k] = __expf(trans[n * 32 + k]);

    float* vrow = &vb[wave][pl][0];
    float v  = __expf(trans[n * 32 + p] + fl[n]);
    float sg = 0.f;
    for (int s = 1; s < L_CHUNK; ++s) {
        vrow[n] = v;
        __builtin_amdgcn_s_waitcnt(0xC07F);   // lgkmcnt(0): wave-coherent LDS
        float a0 = 0.f, a1 = 0.f, a2 = 0.f, a3 = 0.f;
#pragma unroll
        for (int q = 0; q < 8; ++q) {
            const float4 wv = *(const float4*)&vrow[q * 4];
            a0 = __builtin_fmaf(et[q * 4 + 0], wv.x, a0);
            a1 = __builtin_fmaf(et[q * 4 + 1], wv.y, a1);
            a2 = __builtin_fmaf(et[q * 4 + 2], wv.z, a2);
            a3 = __builtin_fmaf(et[q * 4 + 3], wv.w, a3);
        }
        v = __expf(fl[s * 32 + n]) * ((a0 + a1) + (a2 + a3));
        if ((s & 7) == 7) {
            float m = v;
#pragma unroll
            for (int off = 16; off; off >>= 1) m = fmaxf(m, __shfl_xor(m, off, 32));
            if (m > 0.f) { v *= 1.0f / m; sg += __logf(m); }
        }
    }
    QTb[(size_t)(c * 32 + p) * 32 + n] = (bf16_t)v;
    Qnb[(size_t)(c * 32 + n) * 32 + p] = (bf16_t)v;
    if (n == 0) sigma[c * 32 + p] = sg;
}

// ---------------- final: gold + MFMA tree fold + NLL, one block ------------
// Combine op (R later, L earlier): C = (Q_R diag(e^{sigR-mm})) @ Q_L;
// per-column max cm; Qout = C/cm; sigOut = sigL + mm + log cm.
#define QPITCH 40   // bf16 row pitch: multiple of 8 (b128-aligned), bank-skewed

__global__ __launch_bounds__(1024) void final_k(const bf16_t* __restrict__ Qnb,
                                                const bf16_t* __restrict__ QTb,
                                                const float* __restrict__ sgg,
                                                const float* __restrict__ trans,
                                                const float* __restrict__ Fp,
                                                const float* __restrict__ b2,
                                                const int* __restrict__ lab,
                                                float* __restrict__ out) {
    __shared__ bf16_t Qs[32][32][QPITCH];   // 80 KB, slot-major row-major
    __shared__ float sig[32][32];
    __shared__ float gred[16];
    __shared__ float gold_s;

    const int tid  = threadIdx.x;
    const int wv   = tid >> 6, lane = tid & 63;
    const int lrow = lane & 15, quad = lane >> 4;

    // ---- gold score from Fp partials ----
    {
        float ga = 0.f;
        for (int s = tid; s < S_LEN; s += 1024) {
            const int tg = lab[s];
            const float* fp = Fp + (size_t)(s * 8) * T_TAG + tg;
#pragma unroll
            for (int yy = 0; yy < 8; ++yy) ga += fp[yy * T_TAG];
            ga += b2[tg];
            const int tp = (s == 0) ? START_TAG : lab[s - 1];
            ga += trans[tg * T_TAG + tp];
        }
        if (tid == 0) ga += trans[STOP_TAG * T_TAG + lab[S_LEN - 1]];
#pragma unroll
        for (int off = 32; off; off >>= 1) ga += __shfl_down(ga, off, 64);
        if (lane == 0) gred[wv] = ga;
    }

    // ---- level 0: 32 products from global (2 per wave), write LDS ----
#pragma unroll
    for (int rep = 0; rep < 2; ++rep) {
        const int i = wv + rep * 16;
        const int Rc = 2 * i + 1, Lc = 2 * i;
        // sigma_R, mmax, w
        const float4 sr0 = *(const float4*)&sgg[Rc * 32 + quad * 8];
        const float4 sr1 = *(const float4*)&sgg[Rc * 32 + quad * 8 + 4];
        float mloc = fmaxf(fmaxf(fmaxf(sr0.x, sr0.y), fmaxf(sr0.z, sr0.w)),
                           fmaxf(fmaxf(sr1.x, sr1.y), fmaxf(sr1.z, sr1.w)));
        mloc = fmaxf(mloc, __shfl_xor(mloc, 16, 64));
        const float mm = fmaxf(mloc, __shfl_xor(mloc, 32, 64));
        float w[8] = {__expf(sr0.x - mm), __expf(sr0.y - mm), __expf(sr0.z - mm), __expf(sr0.w - mm),
                      __expf(sr1.x - mm), __expf(sr1.y - mm), __expf(sr1.z - mm), __expf(sr1.w - mm)};
        // frags
        bf16x8 a[2], b[2];
#pragma unroll
        for (int mt = 0; mt < 2; ++mt) {
            const bf16x8 qa = *(const bf16x8*)&Qnb[(size_t)(Rc * 32 + mt * 16 + lrow) * 32 + quad * 8];
#pragma unroll
            for (int j = 0; j < 8; ++j) a[mt][j] = (bf16_t)((float)qa[j] * w[j]);
        }
#pragma unroll
        for (int nt = 0; nt < 2; ++nt)
            b[nt] = *(const bf16x8*)&QTb[(size_t)(Lc * 32 + nt * 16 + lrow) * 32 + quad * 8];
        f32x4 acc[2][2] = {};
#pragma unroll
        for (int mt = 0; mt < 2; ++mt)
#pragma unroll
            for (int nt = 0; nt < 2; ++nt)
                acc[mt][nt] = __builtin_amdgcn_mfma_f32_16x16x32_bf16(a[mt], b[nt], acc[mt][nt], 0, 0, 0);
        // per-column renorm
        float cm[2];
#pragma unroll
        for (int nt = 0; nt < 2; ++nt) {
            float m = 0.f;
#pragma unroll
            for (int mt = 0; mt < 2; ++mt)
#pragma unroll
                for (int r = 0; r < 4; ++r) m = fmaxf(m, acc[mt][nt][r]);
            m = fmaxf(m, __shfl_xor(m, 16, 64));
            m = fmaxf(m, __shfl_xor(m, 32, 64));
            cm[nt] = fmaxf(m, 1e-37f);
        }
#pragma unroll
        for (int mt = 0; mt < 2; ++mt)
#pragma unroll
            for (int nt = 0; nt < 2; ++nt) {
                const float inv = 1.0f / cm[nt];
#pragma unroll
                for (int r = 0; r < 4; ++r)
                    Qs[i][mt * 16 + quad * 4 + r][nt * 16 + lrow] = (bf16_t)(acc[mt][nt][r] * inv);
            }
        if (quad == 0) {
#pragma unroll
            for (int nt = 0; nt < 2; ++nt) {
                const int p = nt * 16 + lrow;
                sig[i][p] = sgg[Lc * 32 + p] + mm + __logf(cm[nt]);
            }
        }
    }
    __syncthreads();

    // ---- levels 1..5: in-LDS tree, P = 16,8,4,2,1 ----
    for (int P = 16; P >= 1; P >>= 1) {
        const bool act = (wv < P);
        f32x4 acc[2][2] = {};
        float cm[2] = {1.f, 1.f}, mm = 0.f, sl[2] = {0.f, 0.f};
        if (act) {
            const int i = wv, Rc = 2 * i + 1, Lc = 2 * i;
            const float4 sr0 = *(const float4*)&sig[Rc][quad * 8];
            const float4 sr1 = *(const float4*)&sig[Rc][quad * 8 + 4];
            float mloc = fmaxf(fmaxf(fmaxf(sr0.x, sr0.y), fmaxf(sr0.z, sr0.w)),
                               fmaxf(fmaxf(sr1.x, sr1.y), fmaxf(sr1.z, sr1.w)));
            mloc = fmaxf(mloc, __shfl_xor(mloc, 16, 64));
            mm = fmaxf(mloc, __shfl_xor(mloc, 32, 64));
            float w[8] = {__expf(sr0.x - mm), __expf(sr0.y - mm), __expf(sr0.z - mm), __expf(sr0.w - mm),
                          __expf(sr1.x - mm), __expf(sr1.y - mm), __expf(sr1.z - mm), __expf(sr1.w - mm)};
            bf16x8 a[2], b[2];
#pragma unroll
            for (int mt = 0; mt < 2; ++mt) {
                const bf16x8 qa = *(const bf16x8*)&Qs[Rc][mt * 16 + lrow][quad * 8];
#pragma unroll
                for (int j = 0; j < 8; ++j) a[mt][j] = (bf16_t)((float)qa[j] * w[j]);
            }
#pragma unroll
            for (int nt = 0; nt < 2; ++nt) {
#pragma unroll
                for (int j = 0; j < 8; ++j)
                    b[nt][j] = Qs[Lc][quad * 8 + j][nt * 16 + lrow];   // Q_L[k][n]
            }
#pragma unroll
            for (int nt = 0; nt < 2; ++nt)
                sl[nt] = sig[Lc][nt * 16 + lrow];
#pragma unroll
            for (int mt = 0; mt < 2; ++mt)
#pragma unroll
                for (int nt = 0; nt < 2; ++nt)
                    acc[mt][nt] = __builtin_amdgcn_mfma_f32_16x16x32_bf16(a[mt], b[nt], acc[mt][nt], 0, 0, 0);
#pragma unroll
            for (int nt = 0; nt < 2; ++nt) {
                float m = 0.f;
#pragma unroll
                for (int mt = 0; mt < 2; ++mt)
#pragma unroll
                    for (int r = 0; r < 4; ++r) m = fmaxf(m, acc[mt][nt][r]);
                m = fmaxf(m, __shfl_xor(m, 16, 64));
                m = fmaxf(m, __shfl_xor(m, 32, 64));
                cm[nt] = fmaxf(m, 1e-37f);
            }
        }
        __syncthreads();   // all reads of Qs/sig done
        if (act) {
            const int i = wv;
#pragma unroll
            for (int mt = 0; mt < 2; ++mt)
#pragma unroll
                for (int nt = 0; nt < 2; ++nt) {
                    const float inv = 1.0f / cm[nt];
#pragma unroll
                    for (int r = 0; r < 4; ++r)
                        Qs[i][mt * 16 + quad * 4 + r][nt * 16 + lrow] = (bf16_t)(acc[mt][nt][r] * inv);
                }
            if (quad == 0) {
#pragma unroll
                for (int nt = 0; nt < 2; ++nt)
                    sig[i][nt * 16 + lrow] = sl[nt] + mm + __logf(cm[nt]);
            }
        }
        __syncthreads();
    }

    // ---- finalize ----
    if (tid == 0) {
        float s = 0.f;
#pragma unroll
        for (int i = 0; i < 16; ++i) s += gred[i];
        gold_s = s;
    }
    __syncthreads();
    if (tid < 32) {
        float v = (float)Qs[0][tid][START_TAG] * __expf(trans[STOP_TAG * T_TAG + tid]);
#pragma unroll
        for (int off = 16; off; off >>= 1) v += __shfl_xor(v, off, 32);
        if (tid == 0) out[0] = sig[0][START_TAG] + __logf(v) - gold_s;
    }
}

// ---------------- launch ----------------
extern "C" void kernel_launch(void* const* d_in, const int* in_sizes, int n_in,
                              void* d_out, int out_size, void* d_ws, size_t ws_size,
                              hipStream_t stream) {
    const int*   ctx   = (const int*)d_in[0];
    const float* gz    = (const float*)d_in[1];
    const int*   lab   = (const int*)d_in[2];
    const float* emb   = (const float*)d_in[3];
    const float* w1    = (const float*)d_in[4];
    const float* b1    = (const float*)d_in[5];
    const float* w2    = (const float*)d_in[6];
    const float* b2    = (const float*)d_in[7];
    const float* trans = (const float*)d_in[8];
    float* out = (float*)d_out;

    char* ws = (char*)d_ws;
    bf16_t* Xb  = (bf16_t*)(ws + 0);               // 8192*3456*2 = 56,623,104
    bf16_t* W1b = (bf16_t*)(ws + 56623104);        // 1024*3456*2 =  7,077,888
    float*  Fp  = (float*)(ws + 63700992);         // 8192*8*32*4 =  8,388,608
    bf16_t* Qnb = (bf16_t*)(ws + 72089600);        // 64*32*32*2  =    131,072
    bf16_t* QTb = (bf16_t*)(ws + 72220672);        // 64*32*32*2  =    131,072
    float*  sg  = (float*)(ws + 72351744);         // 64*32*4     =      8,192

    build_all<<<S_LEN + H_DIM, 256, 0, stream>>>(ctx, gz, emb, w1, Xb, W1b);
    gemm_feats<<<512, 256, 0, stream>>>(Xb, W1b, b1, w2, Fp);
    crfA<<<K_CHUNKS * 4, 256, 0, stream>>>(Fp, b2, trans, Qnb, QTb, sg);
    final_k<<<1, 1024, 0, stream>>>(Qnb, QTb, sg, trans, Fp, b2, lab, out);
}